// Round 1
// baseline (107.695 us; speedup 1.0000x reference)
//
#include <hip/hip_runtime.h>
#include <float.h>

#define B_CONST 8

// Pack (x,y,z) -> float4(x,y,z, x*x+y*y+z*z) so the hot loop gets the
// self-dot for free and reference points load as one aligned 16B scalar load.
__global__ void hd_pack(const float* __restrict__ p1, const float* __restrict__ p2,
                        float4* __restrict__ o1, float4* __restrict__ o2,
                        int n1, int n2) {
    int i = blockIdx.x * blockDim.x + threadIdx.x;
    if (i < n1) {
        size_t s = 3* (size_t)i;
        float x = p1[s], y = p1[s + 1], z = p1[s + 2];
        o1[i] = make_float4(x, y, z, fmaf(x, x, fmaf(y, y, z * z)));
    } else if (i < n1 + n2) {
        size_t s = 3 * (size_t)(i - n1);
        float x = p2[s], y = p2[s + 1], z = p2[s + 2];
        o2[i - n1] = make_float4(x, y, z, fmaf(x, x, fmaf(y, y, z * z)));
    }
}

// One block = 64 queries x 4 M-chunks (256 threads). Each thread scans M/4
// reference points for one query: t = |y|^2 - 2 x.y via 3 FMA + 1 fmin.
// Partial mins combined across chunks in LDS, then max over the 64 queries,
// then one uint-bits atomicMax per (dir,batch). Squared distances are
// non-negative so float-bit order == uint order.
__global__ __launch_bounds__(256) void hd_nnmax(
    const float4* __restrict__ pk1, const float4* __restrict__ pk2,
    unsigned int* __restrict__ bmax, int N, int M, int blocksDir0) {
    int blk = blockIdx.x;
    const float4* q; const float4* r; int QN, RM; unsigned int* outp;
    if (blk < blocksDir0) { q = pk1; r = pk2; QN = N; RM = M; outp = bmax; }
    else { blk -= blocksDir0; q = pk2; r = pk1; QN = M; RM = N; outp = bmax + B_CONST; }

    int blocksPerBatch = QN >> 6;                    // 64 queries per block
    int b  = blk / blocksPerBatch;
    int n0 = (blk - b * blocksPerBatch) << 6;
    int qi = threadIdx.x & 63;
    // wave-uniform chunk index -> uniform ref-point address -> s_load path
    int chunk = __builtin_amdgcn_readfirstlane((int)(threadIdx.x >> 6));  // 0..3

    float4 qv = q[(size_t)b * QN + n0 + qi];
    float nx = -2.0f * qv.x, ny = -2.0f * qv.y, nz = -2.0f * qv.z;
    float x2 = qv.w;

    int len = RM >> 2;                               // ref points per chunk
    const float4* rb = r + (size_t)b * RM + (size_t)chunk * len;

    float m0 = FLT_MAX, m1 = FLT_MAX, m2 = FLT_MAX, m3 = FLT_MAX;
    #pragma unroll 2
    for (int j = 0; j < len; j += 4) {
        float4 r0 = rb[j + 0];
        float4 r1 = rb[j + 1];
        float4 r2 = rb[j + 2];
        float4 r3 = rb[j + 3];
        float t0 = fmaf(nz, r0.z, fmaf(ny, r0.y, fmaf(nx, r0.x, r0.w)));
        float t1 = fmaf(nz, r1.z, fmaf(ny, r1.y, fmaf(nx, r1.x, r1.w)));
        float t2 = fmaf(nz, r2.z, fmaf(ny, r2.y, fmaf(nx, r2.x, r2.w)));
        float t3 = fmaf(nz, r3.z, fmaf(ny, r3.y, fmaf(nx, r3.x, r3.w)));
        m0 = fminf(m0, t0);
        m1 = fminf(m1, t1);
        m2 = fminf(m2, t2);
        m3 = fminf(m3, t3);
    }
    float tmin = fminf(fminf(m0, m1), fminf(m2, m3));

    __shared__ float red[256];
    red[threadIdx.x] = tmin;
    __syncthreads();
    if (threadIdx.x < 64) {
        float mm = fminf(fminf(red[threadIdx.x], red[threadIdx.x + 64]),
                         fminf(red[threadIdx.x + 128], red[threadIdx.x + 192]));
        float dist = x2 + mm;                        // true min_m d for this query
        #pragma unroll
        for (int off = 32; off > 0; off >>= 1)
            dist = fmaxf(dist, __shfl_down(dist, off, 64));
        if (threadIdx.x == 0)
            atomicMax(&outp[b], __float_as_uint(dist));
    }
}

__global__ void hd_combine(const unsigned int* __restrict__ bmax, float* __restrict__ out) {
    if (threadIdx.x == 0 && blockIdx.x == 0) {
        float s = 0.0f;
        for (int b = 0; b < B_CONST; ++b)
            s += fmaxf(__uint_as_float(bmax[b]), __uint_as_float(bmax[B_CONST + b]));
        out[0] = s;
    }
}

extern "C" void kernel_launch(void* const* d_in, const int* in_sizes, int n_in,
                              void* d_out, int out_size, void* d_ws, size_t ws_size,
                              hipStream_t stream) {
    const float* p1 = (const float*)d_in[0];
    const float* p2 = (const float*)d_in[1];
    const int B = B_CONST;
    int N = in_sizes[0] / (3 * B);
    int M = in_sizes[1] / (3 * B);
    int n1 = B * N, n2 = B * M;

    char* ws = (char*)d_ws;
    float4* pk1 = (float4*)ws;
    float4* pk2 = (float4*)(ws + (size_t)n1 * sizeof(float4));
    unsigned int* bmax = (unsigned int*)(ws + (size_t)(n1 + n2) * sizeof(float4));

    // ws is re-poisoned to 0xAA before every launch: clear the atomicMax slots.
    hipMemsetAsync(bmax, 0, 2 * B * sizeof(unsigned int), stream);

    int packBlocks = (n1 + n2 + 255) / 256;
    hd_pack<<<packBlocks, 256, 0, stream>>>(p1, p2, pk1, pk2, n1, n2);

    int blocksDir0 = n1 >> 6;   // 64 queries per block
    int blocksDir1 = n2 >> 6;
    hd_nnmax<<<blocksDir0 + blocksDir1, 256, 0, stream>>>(pk1, pk2, bmax, N, M, blocksDir0);

    hd_combine<<<1, 64, 0, stream>>>(bmax, (float*)d_out);
}

// Round 2
// 105.348 us; speedup vs baseline: 1.0223x; 1.0223x over previous
//
#include <hip/hip_runtime.h>
#include <float.h>

#define B_CONST 8

typedef float v2f __attribute__((ext_vector_type(2)));

// Pack (x,y,z) -> SoA point-pairs: for points (2j,2j+1) emit
// [x0 x1 | y0 y1 | z0 z1 | w0 w1] (32B per pair, w = |p|^2).
// This feeds v_pk_fma_f32 in the hot loop with one s_load_dwordx8 per pair.
// Also zeroes the 16 atomicMax slots (replaces a separate memset node).
__global__ void hd_pack(const float* __restrict__ p1, const float* __restrict__ p2,
                        float* __restrict__ o1, float* __restrict__ o2,
                        int n1, int n2, unsigned int* __restrict__ bmax) {
    int i = blockIdx.x * blockDim.x + threadIdx.x;
    if (blockIdx.x == 0 && threadIdx.x < 2 * B_CONST) bmax[threadIdx.x] = 0u;
    const float* src; float* dst; int idx;
    if (i < n1)            { src = p1; dst = o1; idx = i; }
    else if (i < n1 + n2)  { src = p2; dst = o2; idx = i - n1; }
    else return;
    size_t s = 3 * (size_t)idx;
    float x = src[s], y = src[s + 1], z = src[s + 2];
    float w = fmaf(x, x, fmaf(y, y, z * z));
    float* base = dst + (size_t)(idx >> 1) * 8 + (idx & 1);
    base[0] = x; base[2] = y; base[4] = z; base[6] = w;
}

// One block = 64 queries x 8 M-chunks (512 threads, 8 waves -> full occupancy).
// Each thread scans RM/8 reference points for one query, 2 points per packed
// iteration: t01 = w01 + nx*x01 + ny*y01 + nz*z01 via 3 v_pk_fma_f32 + 2 v_min.
// Ref addresses are wave-uniform -> SMEM s_load path (no VMEM in hot loop).
__global__ __launch_bounds__(512) void hd_nnmax(
    const float* __restrict__ p1raw, const float* __restrict__ p2raw,
    const float* __restrict__ pk1, const float* __restrict__ pk2,
    unsigned int* __restrict__ bmax, int N, int M, int blocksDir0) {
    int blk = blockIdx.x;
    const float* qraw; const float* rpk; int QN, RM; unsigned int* outp;
    if (blk < blocksDir0) { qraw = p1raw; rpk = pk2; QN = N; RM = M; outp = bmax; }
    else { blk -= blocksDir0; qraw = p2raw; rpk = pk1; QN = M; RM = N; outp = bmax + B_CONST; }

    int bpb = QN >> 6;                       // blocks per batch (64 queries/block)
    int b  = blk / bpb;
    int n0 = (blk - b * bpb) << 6;
    int qi = threadIdx.x & 63;
    int chunk = __builtin_amdgcn_readfirstlane((int)(threadIdx.x >> 6));  // 0..7

    // Query from the raw input (3 consecutive floats per lane).
    size_t g = (size_t)b * QN + n0 + qi;
    float x = qraw[3 * g], y = qraw[3 * g + 1], z = qraw[3 * g + 2];
    float x2 = fmaf(x, x, fmaf(y, y, z * z));
    v2f NX = { -2.0f * x, -2.0f * x };
    v2f NY = { -2.0f * y, -2.0f * y };
    v2f NZ = { -2.0f * z, -2.0f * z };

    int pkPerBatch = RM >> 1;                // point-pairs per batch
    int pkPerChunk = RM >> 4;                // point-pairs per chunk (8 chunks)
    const v2f* rb = (const v2f*)rpk +
        ((size_t)b * pkPerBatch + (size_t)chunk * pkPerChunk) * 4;  // 4 v2f per pair

    v2f mA = { FLT_MAX, FLT_MAX };
    v2f mB = { FLT_MAX, FLT_MAX };
    #pragma unroll 2
    for (int k = 0; k < pkPerChunk; k += 4) {
        const v2f* p = rb + (size_t)k * 4;
        v2f a0 = p[3];
        a0 = __builtin_elementwise_fma(NX, p[0], a0);
        a0 = __builtin_elementwise_fma(NY, p[1], a0);
        a0 = __builtin_elementwise_fma(NZ, p[2], a0);
        mA = __builtin_elementwise_min(mA, a0);
        v2f a1 = p[7];
        a1 = __builtin_elementwise_fma(NX, p[4], a1);
        a1 = __builtin_elementwise_fma(NY, p[5], a1);
        a1 = __builtin_elementwise_fma(NZ, p[6], a1);
        mB = __builtin_elementwise_min(mB, a1);
        v2f a2 = p[11];
        a2 = __builtin_elementwise_fma(NX, p[8], a2);
        a2 = __builtin_elementwise_fma(NY, p[9], a2);
        a2 = __builtin_elementwise_fma(NZ, p[10], a2);
        mA = __builtin_elementwise_min(mA, a2);
        v2f a3 = p[15];
        a3 = __builtin_elementwise_fma(NX, p[12], a3);
        a3 = __builtin_elementwise_fma(NY, p[13], a3);
        a3 = __builtin_elementwise_fma(NZ, p[14], a3);
        mB = __builtin_elementwise_min(mB, a3);
    }
    v2f mm2 = __builtin_elementwise_min(mA, mB);
    float tmin = fminf(mm2.x, mm2.y);

    __shared__ float red[512];
    red[threadIdx.x] = tmin;
    __syncthreads();
    if (threadIdx.x < 64) {
        float mm = red[qi];
        #pragma unroll
        for (int c = 1; c < 8; ++c) mm = fminf(mm, red[qi + 64 * c]);
        float dist = x2 + mm;                // true min_m d for this query
        #pragma unroll
        for (int off = 32; off > 0; off >>= 1)
            dist = fmaxf(dist, __shfl_down(dist, off, 64));
        if (threadIdx.x == 0)
            atomicMax(&outp[b], __float_as_uint(dist));
    }
}

__global__ void hd_combine(const unsigned int* __restrict__ bmax, float* __restrict__ out) {
    if (threadIdx.x == 0 && blockIdx.x == 0) {
        float s = 0.0f;
        for (int b = 0; b < B_CONST; ++b)
            s += fmaxf(__uint_as_float(bmax[b]), __uint_as_float(bmax[B_CONST + b]));
        out[0] = s;
    }
}

extern "C" void kernel_launch(void* const* d_in, const int* in_sizes, int n_in,
                              void* d_out, int out_size, void* d_ws, size_t ws_size,
                              hipStream_t stream) {
    const float* p1 = (const float*)d_in[0];
    const float* p2 = (const float*)d_in[1];
    const int B = B_CONST;
    int N = in_sizes[0] / (3 * B);
    int M = in_sizes[1] / (3 * B);
    int n1 = B * N, n2 = B * M;

    char* ws = (char*)d_ws;
    float* pk1 = (float*)ws;
    float* pk2 = (float*)(ws + (size_t)n1 * 4 * sizeof(float));
    unsigned int* bmax = (unsigned int*)(ws + (size_t)(n1 + n2) * 4 * sizeof(float));

    int packBlocks = (n1 + n2 + 255) / 256;
    hd_pack<<<packBlocks, 256, 0, stream>>>(p1, p2, pk1, pk2, n1, n2, bmax);

    int blocksDir0 = n1 >> 6;   // 64 queries per block
    int blocksDir1 = n2 >> 6;
    hd_nnmax<<<blocksDir0 + blocksDir1, 512, 0, stream>>>(p1, p2, pk1, pk2, bmax, N, M, blocksDir0);

    hd_combine<<<1, 64, 0, stream>>>(bmax, (float*)d_out);
}

// Round 3
// 83.683 us; speedup vs baseline: 1.2870x; 1.2589x over previous
//
#include <hip/hip_runtime.h>
#include <float.h>

#define B_CONST 8
#define GROUPS 4          // ref-dim split across blocks (combined via atomicMin)
#define FLT_MAX_BITS 0x7F7FFFFFu

typedef float v2f __attribute__((ext_vector_type(2)));

// Pack (x,y,z) -> float4(x,y,z,|p|^2), coalesced dwordx4 stores.
// Also init qmin[n1+n2]=FLT_MAX bits, bmax[8]=0, counter=0 (extra graph nodes avoided).
__global__ void hd_pack(const float* __restrict__ p1, const float* __restrict__ p2,
                        float4* __restrict__ o1, float4* __restrict__ o2,
                        unsigned int* __restrict__ qmin, unsigned int* __restrict__ bmax,
                        int n1, int n2) {
    int i = blockIdx.x * blockDim.x + threadIdx.x;
    if (i < n1 + n2) qmin[i] = FLT_MAX_BITS;
    if (blockIdx.x == 0 && threadIdx.x < B_CONST + 1)
        bmax[threadIdx.x] = 0u;                    // bmax[0..7] = 0, [8] = ticket counter
    const float* src; float4* dst; int idx;
    if (i < n1)           { src = p1; dst = o1; idx = i; }
    else if (i < n1 + n2) { src = p2; dst = o2; idx = i - n1; }
    else return;
    size_t s = 3 * (size_t)idx;
    float x = src[s], y = src[s + 1], z = src[s + 2];
    dst[idx] = make_float4(x, y, z, fmaf(x, x, fmaf(y, y, z * z)));
}

// Block = 512 queries x 8 wave-chunks of one ref group. Each thread holds
// Q=8 queries (4 packed pairs); each uniform ref point (16B s_load, SGPR
// broadcast) feeds 16 packed VALU ops -> scalar feed amortized 8x vs r2.
// 8 wave-partials combined in LDS, then one atomicMin per query.
__global__ __launch_bounds__(512) void hd_nnmax(
    const float4* __restrict__ qpt1, const float4* __restrict__ qpt2,
    unsigned int* __restrict__ qmin, int N, int M, int blocksDir0) {
    int blk = blockIdx.x;
    const float4* q; const float4* r; int QN, RM; unsigned int* qm;
    if (blk < blocksDir0) { q = qpt1; r = qpt2; QN = N; RM = M; qm = qmin; }
    else { blk -= blocksDir0; q = qpt2; r = qpt1; QN = M; RM = N; qm = qmin + B_CONST * N; }

    int qblocks = QN >> 9;                       // 512 queries per block
    int perB = qblocks * GROUPS;
    int b    = blk / perB;
    int rem  = blk - b * perB;
    int qblk = rem / GROUPS;
    int g    = rem - qblk * GROUPS;

    int l = threadIdx.x & 63;
    int w = __builtin_amdgcn_readfirstlane((int)(threadIdx.x >> 6));   // 0..7

    // Load 8 queries per thread: slot s -> query qblk*512 + s*64 + l (coalesced).
    const float4* qb = q + (size_t)b * QN + ((size_t)qblk << 9);
    float4 qv[8];
    #pragma unroll
    for (int s = 0; s < 8; ++s) qv[s] = qb[s * 64 + l];
    v2f NX[4], NY[4], NZ[4], MN[4];
    #pragma unroll
    for (int p = 0; p < 4; ++p) {
        NX[p] = (v2f){ -2.0f * qv[2*p].x, -2.0f * qv[2*p+1].x };
        NY[p] = (v2f){ -2.0f * qv[2*p].y, -2.0f * qv[2*p+1].y };
        NZ[p] = (v2f){ -2.0f * qv[2*p].z, -2.0f * qv[2*p+1].z };
        MN[p] = (v2f){ FLT_MAX, FLT_MAX };
    }

    // This wave's ref chunk: RM/32 points (GROUPS=4 groups x 8 waves).
    int cnt = RM >> 5;
    const float4* rb = r + (size_t)b * RM + (size_t)g * (RM >> 2) + (size_t)w * cnt;

    #pragma unroll 8
    for (int j = 0; j < cnt; ++j) {
        float4 rf = rb[j];                      // wave-uniform -> s_load_dwordx4
        v2f rx = (v2f){ rf.x, rf.x };
        v2f ry = (v2f){ rf.y, rf.y };
        v2f rz = (v2f){ rf.z, rf.z };
        v2f rw = (v2f){ rf.w, rf.w };
        #pragma unroll
        for (int p = 0; p < 4; ++p) {
            v2f a = __builtin_elementwise_fma(NX[p], rx, rw);
            a = __builtin_elementwise_fma(NY[p], ry, a);
            a = __builtin_elementwise_fma(NZ[p], rz, a);
            MN[p] = __builtin_elementwise_min(MN[p], a);
        }
    }

    // Combine the 8 wave-partials per query in LDS.
    __shared__ float red[4096];                 // [wave][query-in-block]
    #pragma unroll
    for (int p = 0; p < 4; ++p) {
        red[(w << 9) + (2*p)     * 64 + l] = MN[p].x;
        red[(w << 9) + (2*p + 1) * 64 + l] = MN[p].y;
    }
    __syncthreads();
    int t = threadIdx.x;                        // query-in-block index
    float m = red[t];
    #pragma unroll
    for (int ww = 1; ww < 8; ++ww) m = fminf(m, red[(ww << 9) + t]);
    float4 qq = qb[t];                          // reload for |x|^2 (L1/L2 hit)
    float dist = fmaxf(qq.w + m, 0.0f);         // clamp: dists are >=0 up to rounding
    atomicMin(qm + (size_t)b * QN + ((size_t)qblk << 9) + t, __float_as_uint(dist));
}

// 16 blocks, one per (dir,b): uint-max over the 4096 per-query mins (bits of
// non-negative floats order like uints), atomicMax into bmax[b] (covers the
// max over both directions), last block sums bmax[0..7] into out[0].
__global__ __launch_bounds__(256) void hd_final(
    const unsigned int* __restrict__ qmin, unsigned int* __restrict__ bmax,
    float* __restrict__ out, int N, int M) {
    int dir = blockIdx.x >> 3;
    int b   = blockIdx.x & 7;
    int cnt = dir ? M : N;
    const unsigned int* src = qmin + (dir ? (size_t)B_CONST * N + (size_t)b * M
                                          : (size_t)b * N);
    unsigned int mx = 0u;
    for (int i = threadIdx.x; i < cnt; i += 256) mx = max(mx, src[i]);
    #pragma unroll
    for (int off = 32; off > 0; off >>= 1)
        mx = max(mx, (unsigned int)__shfl_down((int)mx, off, 64));
    __shared__ unsigned int wmax[4];
    if ((threadIdx.x & 63) == 0) wmax[threadIdx.x >> 6] = mx;
    __syncthreads();
    if (threadIdx.x == 0) {
        mx = max(max(wmax[0], wmax[1]), max(wmax[2], wmax[3]));
        atomicMax(&bmax[b], mx);
        __threadfence();
        unsigned int ticket = atomicAdd(&bmax[B_CONST], 1u);  // bmax[8] = counter
        if (ticket == 15u) {                    // last of the 16 blocks
            float s = 0.0f;
            for (int bb = 0; bb < B_CONST; ++bb)
                s += __uint_as_float(atomicMax(&bmax[bb], 0u));  // coherent read
            out[0] = s;
        }
    }
}

extern "C" void kernel_launch(void* const* d_in, const int* in_sizes, int n_in,
                              void* d_out, int out_size, void* d_ws, size_t ws_size,
                              hipStream_t stream) {
    const float* p1 = (const float*)d_in[0];
    const float* p2 = (const float*)d_in[1];
    const int B = B_CONST;
    int N = in_sizes[0] / (3 * B);
    int M = in_sizes[1] / (3 * B);
    int n1 = B * N, n2 = B * M;

    char* ws = (char*)d_ws;
    float4* qpt1 = (float4*)ws;
    float4* qpt2 = (float4*)(ws + (size_t)n1 * sizeof(float4));
    unsigned int* qmin = (unsigned int*)(ws + (size_t)(n1 + n2) * sizeof(float4));
    unsigned int* bmax = qmin + (n1 + n2);      // [0..7]=per-batch max, [8]=ticket

    int packBlocks = (n1 + n2 + 255) / 256;
    hd_pack<<<packBlocks, 256, 0, stream>>>(p1, p2, qpt1, qpt2, qmin, bmax, n1, n2);

    int blocksDir0 = B * (N >> 9) * GROUPS;
    int blocksDir1 = B * (M >> 9) * GROUPS;
    hd_nnmax<<<blocksDir0 + blocksDir1, 512, 0, stream>>>(qpt1, qpt2, qmin, N, M, blocksDir0);

    hd_final<<<16, 256, 0, stream>>>(qmin, bmax, (float*)d_out, N, M);
}